// Round 10
// baseline (2578.697 us; speedup 1.0000x reference)
//
#include <hip/hip_runtime.h>
#include <cstdint>
#include <cstddef>

#define EDIM 256
#define HID  512
#define NTAG 12
#define HDIM 256
#define BB   64
#define SS   256
#define START_TAG 10
#define STOP_TAG  11
#define NEGV (-10000.0f)
#define UPW  8           // h-units per WG per direction (32 gate rows)

typedef __attribute__((ext_vector_type(8))) short bf16x8;
typedef __attribute__((ext_vector_type(4))) float f32x4;

__device__ __forceinline__ unsigned short bf16_rne(float x) {
  union { float f; unsigned u; } a; a.f = x;
  return (unsigned short)((a.u + 0x7fffu + ((a.u >> 16) & 1u)) >> 16);
}
__device__ __forceinline__ float bf16_tof(unsigned short h) {
  union { unsigned u; float f; } a; a.u = ((unsigned)h) << 16; return a.f;
}
__device__ __forceinline__ void unpack8(const unsigned* u, bf16x8& hi, bf16x8& lo) {
#pragma unroll
  for (int j = 0; j < 8; ++j) {
    hi[j] = (short)(u[j] & 0xffffu);
    lo[j] = (short)(u[j] >> 16);
  }
}
__device__ __forceinline__ void pack_hilo(const float* xf, bf16x8& hi, bf16x8& lo) {
#pragma unroll
  for (int j = 0; j < 8; ++j) {
    unsigned short hb = bf16_rne(xf[j]);
    hi[j] = (short)hb;
    lo[j] = (short)bf16_rne(xf[j] - bf16_tof(hb));
  }
}

// ---------------- K0: gather + split-bf16 pack  xpk[t][b][k] ---------------
__global__ void k0_gather(const int* __restrict__ sent,
                          const float* __restrict__ emb,
                          unsigned int* __restrict__ xpk) {
  int t = blockIdx.x;
  for (int n = threadIdx.x; n < BB * EDIM; n += 256) {
    int b = n >> 8, k = n & 255;
    int tok = sent[b * SS + t];
    float x = emb[(size_t)tok * EDIM + k];
    unsigned short hb = bf16_rne(x);
    unsigned short lb = bf16_rne(x - bf16_tof(hb));
    xpk[((size_t)t * BB + b) * EDIM + k] = (unsigned)hb | ((unsigned)lb << 16);
  }
}

// ---------------- K1: input projection via split-bf16 MFMA (R5-proven) -----
__global__ void __launch_bounds__(256)
k1_mfma(const unsigned int* __restrict__ xpk,
        const float* __restrict__ WihF, const float* __restrict__ WihB,
        const float* __restrict__ bihF, const float* __restrict__ bhhF,
        const float* __restrict__ bihB, const float* __restrict__ bhhB,
        float* __restrict__ pre) {
  int blk = blockIdx.x;
  int rg = blk & 15, t = (blk >> 4) & 255, d = blk >> 12;
  const float* Wih = d ? WihB : WihF;
  const float* bi  = d ? bihB : bihF;
  const float* bh2 = d ? bhhB : bhhF;
  int tid = threadIdx.x, lane = tid & 63, v = tid >> 6;
  int l15 = lane & 15, l4 = lane >> 4;

  int Rrow = rg * 64 + v * 16 + l15;
  const float* wrow = Wih + (size_t)Rrow * EDIM;
  bf16x8 Ahi[8], Alo[8];
#pragma unroll
  for (int kk = 0; kk < 8; ++kk) {
    float4 f0 = *(const float4*)(wrow + kk * 32 + l4 * 8);
    float4 f1 = *(const float4*)(wrow + kk * 32 + l4 * 8 + 4);
    float xf[8] = {f0.x, f0.y, f0.z, f0.w, f1.x, f1.y, f1.z, f1.w};
    pack_hilo(xf, Ahi[kk], Alo[kk]);
  }
  float b4[4];
#pragma unroll
  for (int r = 0; r < 4; ++r) {
    int Racc = rg * 64 + v * 16 + l4 * 4 + r;
    b4[r] = bi[Racc] + bh2[Racc];
  }
  const unsigned int* xt = xpk + (size_t)t * BB * EDIM;
  size_t obase = ((size_t)d * SS + t) * 1024 * BB;
#pragma unroll
  for (int ct = 0; ct < 4; ++ct) {
    f32x4 acc = {b4[0], b4[1], b4[2], b4[3]};
    int col = ct * 16 + l15;
    const unsigned int* xc = xt + (size_t)col * EDIM;
#pragma unroll
    for (int kk = 0; kk < 8; ++kk) {
      uint4 q0 = *(const uint4*)(xc + kk * 32 + l4 * 8);
      uint4 q1 = *(const uint4*)(xc + kk * 32 + l4 * 8 + 4);
      unsigned u[8] = {q0.x, q0.y, q0.z, q0.w, q1.x, q1.y, q1.z, q1.w};
      bf16x8 bhf, blf;
      unpack8(u, bhf, blf);
      acc = __builtin_amdgcn_mfma_f32_16x16x32_bf16(Ahi[kk], bhf, acc, 0, 0, 0);
      acc = __builtin_amdgcn_mfma_f32_16x16x32_bf16(Ahi[kk], blf, acc, 0, 0, 0);
      acc = __builtin_amdgcn_mfma_f32_16x16x32_bf16(Alo[kk], bhf, acc, 0, 0, 0);
    }
#pragma unroll
    for (int r = 0; r < 4; ++r) {
      int Racc = rg * 64 + v * 16 + l4 * 4 + r;
      pre[obase + (size_t)Racc * BB + col] = acc[r];
    }
  }
}

// ---------------- K2: persistent BiLSTM, DIRECTION-INTERLEAVED -------------
// 32 WGs; WG w owns units [w*8,w*8+8) of BOTH directions. Per iteration s:
// segF(s) then segB(s). The fwd produce->detect edge latency elapses during
// segB's compute (and vice versa) — the cross-XCD sync latency leaves the
// serial path. Rings per dir: 4 slots x [k][b] u32 (R5-proven layout,
// single-writer 64B lines). Sentinel 0xFFFFFFFF; poll IS the load.
// Segment order: pre-loads -> poll -> rearm(s+1) -> h-MFMA -> shfl -> acts
// -> vmcnt(0) -> produce -> hseq.
#define MFMA6(HH, HL, bhf, blf)                                               \
  accA = __builtin_amdgcn_mfma_f32_16x16x32_bf16(HH[0][kk], bhf, accA, 0, 0, 0); \
  accB = __builtin_amdgcn_mfma_f32_16x16x32_bf16(HH[0][kk], blf, accB, 0, 0, 0); \
  accC = __builtin_amdgcn_mfma_f32_16x16x32_bf16(HL[0][kk], bhf, accC, 0, 0, 0); \
  accD = __builtin_amdgcn_mfma_f32_16x16x32_bf16(HH[1][kk], bhf, accD, 0, 0, 0); \
  accE = __builtin_amdgcn_mfma_f32_16x16x32_bf16(HH[1][kk], blf, accE, 0, 0, 0); \
  accF = __builtin_amdgcn_mfma_f32_16x16x32_bf16(HL[1][kk], bhf, accF, 0, 0, 0);

#define SEGMENT(DIRC, HhiX, HloX, c2X, ringX, sX)                             \
  {                                                                           \
    const int t = (DIRC) ? (SS - 1 - (sX)) : (sX);                            \
    const float* pbase =                                                      \
        pre + (((size_t)(DIRC) * SS + t) * 1024) * BB + bcol;                 \
    f32x4 accA, accB, accC, accD, accE, accF;                                 \
    _Pragma("unroll")                                                         \
    for (int r = 0; r < 4; ++r) {                                             \
      int i0 = l4 * 4 + r;                                                    \
      int R0 = ((i0 >> 3) << 8) + w * UPW + (i0 & 7);                         \
      accA[r] = pbase[(size_t)R0 * BB];                                       \
      int i1 = 16 + i0;                                                       \
      int R1 = ((i1 >> 3) << 8) + w * UPW + (i1 & 7);                         \
      accD[r] = pbase[(size_t)R1 * BB];                                       \
    }                                                                         \
    accB = (f32x4){0.f, 0.f, 0.f, 0.f}; accC = accB; accE = accB; accF = accB;\
    unsigned uv[64];                                                          \
    if ((sX) > 0) {                                                           \
      const unsigned* slotp =                                                 \
          (ringX) + (size_t)(((sX) - 1) & 3) * 16384 + bcol;                  \
      while (true) {                                                          \
        int bad = 0;                                                          \
        _Pragma("unroll")                                                     \
        for (int kk = 0; kk < 8; ++kk)                                        \
          _Pragma("unroll")                                                   \
          for (int j = 0; j < 8; ++j) {                                       \
            unsigned val = __hip_atomic_load(                                 \
                slotp + (size_t)(kk * 32 + l4 * 8 + j) * BB,                  \
                __ATOMIC_RELAXED, __HIP_MEMORY_SCOPE_AGENT);                  \
            uv[kk * 8 + j] = val;                                             \
            bad |= (val == 0xFFFFFFFFu);                                      \
          }                                                                   \
        if (!__any(bad)) break;                                               \
        __builtin_amdgcn_s_sleep(1);                                          \
      }                                                                       \
      __builtin_amdgcn_sched_barrier(0);                                      \
    }                                                                         \
    {                                                                         \
      unsigned* ra = (ringX) + (size_t)(((sX) + 1) & 3) * 16384;              \
      __hip_atomic_store(ra + (size_t)kg0 * BB + bcol, 0xFFFFFFFFu,           \
                         __ATOMIC_RELAXED, __HIP_MEMORY_SCOPE_AGENT);         \
      __hip_atomic_store(ra + (size_t)(kg0 + 1) * BB + bcol, 0xFFFFFFFFu,     \
                         __ATOMIC_RELAXED, __HIP_MEMORY_SCOPE_AGENT);         \
    }                                                                         \
    if ((sX) == 0) {                                                          \
      const float* hrow = h0 + ((size_t)(DIRC) * BB + bcol) * HDIM;           \
      _Pragma("unroll")                                                       \
      for (int kk = 0; kk < 8; ++kk) {                                        \
        float4 f0 = *(const float4*)(hrow + kk * 32 + l4 * 8);                \
        float4 f1 = *(const float4*)(hrow + kk * 32 + l4 * 8 + 4);            \
        float xf[8] = {f0.x, f0.y, f0.z, f0.w, f1.x, f1.y, f1.z, f1.w};       \
        bf16x8 bhf, blf;                                                      \
        pack_hilo(xf, bhf, blf);                                              \
        MFMA6(HhiX, HloX, bhf, blf)                                           \
      }                                                                       \
    } else {                                                                  \
      _Pragma("unroll")                                                       \
      for (int kk = 0; kk < 8; ++kk) {                                        \
        bf16x8 bhf, blf;                                                      \
        unpack8(&uv[kk * 8], bhf, blf);                                       \
        MFMA6(HhiX, HloX, bhf, blf)                                           \
      }                                                                       \
    }                                                                         \
    f32x4 acc0 = accA + accB + accC;                                          \
    f32x4 acc1 = accD + accE + accF;                                          \
    f32x4 r0, r1;                                                             \
    _Pragma("unroll")                                                         \
    for (int r = 0; r < 4; ++r) {                                             \
      r0[r] = __shfl_xor(acc0[r], 32);                                        \
      r1[r] = __shfl_xor(acc1[r], 32);                                        \
    }                                                                         \
    float hn[2]; unsigned pv[2];                                              \
    _Pragma("unroll")                                                         \
    for (int e = 0; e < 2; ++e) {                                             \
      float iv = low ? acc0[e] : r0[2 + e];                                   \
      float fv = low ? r0[e] : acc0[2 + e];                                   \
      float gv = low ? acc1[e] : r1[2 + e];                                   \
      float ov = low ? r1[e] : acc1[2 + e];                                   \
      float si = 1.f / (1.f + expf(-iv));                                     \
      float sf = 1.f / (1.f + expf(-fv));                                     \
      float so = 1.f / (1.f + expf(-ov));                                     \
      float cn = sf * (c2X)[e] + si * tanhf(gv);                              \
      (c2X)[e] = cn;                                                          \
      float hh = so * tanhf(cn);                                              \
      hn[e] = hh;                                                             \
      unsigned short hb2 = bf16_rne(hh);                                      \
      unsigned short lb2 = bf16_rne(hh - bf16_tof(hb2));                      \
      pv[e] = (unsigned)hb2 | ((unsigned)lb2 << 16);                          \
    }                                                                         \
    asm volatile("s_waitcnt vmcnt(0)" ::: "memory");                          \
    {                                                                         \
      unsigned* pd = (ringX) + (size_t)((sX) & 3) * 16384;                    \
      __hip_atomic_store(pd + (size_t)kg0 * BB + bcol, pv[0],                 \
                         __ATOMIC_RELAXED, __HIP_MEMORY_SCOPE_AGENT);         \
      __hip_atomic_store(pd + (size_t)(kg0 + 1) * BB + bcol, pv[1],           \
                         __ATOMIC_RELAXED, __HIP_MEMORY_SCOPE_AGENT);         \
    }                                                                         \
    hseq[(((size_t)(DIRC) * SS + t) * HDIM + kg0) * BB + bcol] = hn[0];       \
    hseq[(((size_t)(DIRC) * SS + t) * HDIM + kg0 + 1) * BB + bcol] = hn[1];   \
  }

__global__ void __launch_bounds__(256, 1)
lstm_dual(const float* __restrict__ WhhF, const float* __restrict__ WhhB,
          const float* __restrict__ h0, const float* __restrict__ c0,
          const float* __restrict__ pre, float* __restrict__ hseq,
          unsigned int* __restrict__ hx) {
  const int w = blockIdx.x;           // 0..31: unit group (both directions)
  const int tid = threadIdx.x;
  const int lane = tid & 63;
  const int v = tid >> 6;
  const int l15 = lane & 15, l4 = lane >> 4;
  const int bcol = v * 16 + l15;
  const int u2 = ((l4 & 1) << 2) | ((l4 >> 1) << 1);
  const bool low = (l4 < 2);
  const int kg0 = w * UPW + u2;

  // ---- persistent Whh fragments for BOTH directions (256 VGPRs)
  bf16x8 HhiF[2][8], HloF[2][8], HhiB[2][8], HloB[2][8];
#pragma unroll
  for (int rt = 0; rt < 2; ++rt) {
    int i = rt * 16 + l15;
    int R = ((i >> 3) << 8) + w * UPW + (i & 7);
    const float* wrF = WhhF + (size_t)R * HDIM;
    const float* wrB = WhhB + (size_t)R * HDIM;
#pragma unroll
    for (int kk = 0; kk < 8; ++kk) {
      {
        float4 f0 = *(const float4*)(wrF + kk * 32 + l4 * 8);
        float4 f1 = *(const float4*)(wrF + kk * 32 + l4 * 8 + 4);
        float xf[8] = {f0.x, f0.y, f0.z, f0.w, f1.x, f1.y, f1.z, f1.w};
        pack_hilo(xf, HhiF[rt][kk], HloF[rt][kk]);
      }
      {
        float4 f0 = *(const float4*)(wrB + kk * 32 + l4 * 8);
        float4 f1 = *(const float4*)(wrB + kk * 32 + l4 * 8 + 4);
        float xf[8] = {f0.x, f0.y, f0.z, f0.w, f1.x, f1.y, f1.z, f1.w};
        pack_hilo(xf, HhiB[rt][kk], HloB[rt][kk]);
      }
    }
  }
  // ---- register cell state, both dirs: units kg0, kg0+1 at col bcol
  float c2F[2], c2B[2];
  c2F[0] = c0[((size_t)0 * BB + bcol) * HDIM + kg0];
  c2F[1] = c0[((size_t)0 * BB + bcol) * HDIM + kg0 + 1];
  c2B[0] = c0[((size_t)1 * BB + bcol) * HDIM + kg0];
  c2B[1] = c0[((size_t)1 * BB + bcol) * HDIM + kg0 + 1];

  unsigned int* ringF = hx;                     // 4 slots x 16384 u32
  unsigned int* ringB = hx + 4 * 16384;

  for (int s = 0; s < SS; ++s) {
    SEGMENT(0, HhiF, HloF, c2F, ringF, s)
    SEGMENT(1, HhiB, HloB, c2B, ringB, s)
  }
}

// ---------------- K3: feats[t][b][tag] = [hf;hb] . Wt[tag] + bt -----------
__global__ void k3_feats(const float* __restrict__ hseq,
                         const float* __restrict__ Wt,
                         const float* __restrict__ bt,
                         float* __restrict__ feats) {
  int t = blockIdx.x, tid = threadIdx.x;
  __shared__ float Wl[NTAG][HID];
  for (int n = tid; n < NTAG * HID; n += 256) Wl[n >> 9][n & 511] = Wt[n];
  __syncthreads();
  int b = tid & 63, tq = tid >> 6;
  float acc[3];
  for (int c = 0; c < 3; ++c) acc[c] = bt[tq * 3 + c];
  const float* hf = hseq + ((size_t)0 * SS + t) * HDIM * BB;
  const float* hb = hseq + ((size_t)1 * SS + t) * HDIM * BB;
  for (int k = 0; k < HDIM; ++k) {
    float h1 = hf[(size_t)k * BB + b];
    float h2 = hb[(size_t)k * BB + b];
#pragma unroll
    for (int c = 0; c < 3; ++c) {
      acc[c] += h1 * Wl[tq * 3 + c][k];
      acc[c] += h2 * Wl[tq * 3 + c][HDIM + k];
    }
  }
  for (int c = 0; c < 3; ++c)
    feats[((size_t)t * BB + b) * NTAG + tq * 3 + c] = acc[c];
}

// ---------------- K4: Viterbi per batch element ---------------------------
__global__ void k4_viterbi(const float* __restrict__ feats,
                           const float* __restrict__ trans,
                           float* __restrict__ out) {
  int b = blockIdx.x, lane = threadIdx.x;   // 64 threads
  __shared__ float tr[NTAG][NTAG];
  __shared__ float fv[NTAG], fnew[NTAG], term[NTAG];
  __shared__ unsigned char bp[SS][NTAG];
  for (int n = lane; n < NTAG * NTAG; n += 64) tr[n / NTAG][n % NTAG] = trans[n];
  if (lane < NTAG) fv[lane] = (lane == START_TAG) ? 0.f : NEGV;
  __syncthreads();
  for (int s = 0; s < SS; ++s) {
    if (lane < NTAG) {
      float best = fv[0] + tr[lane][0]; int arg = 0;
#pragma unroll
      for (int j = 1; j < NTAG; ++j) {
        float vv = fv[j] + tr[lane][j];
        if (vv > best) { best = vv; arg = j; }
      }
      fnew[lane] = best + feats[((size_t)s * BB + b) * NTAG + lane];
      bp[s][lane] = (unsigned char)arg;
    }
    __syncthreads();
    if (lane < NTAG) fv[lane] = fnew[lane];
    __syncthreads();
  }
  if (lane < NTAG) {
    float vv = fv[lane] + tr[STOP_TAG][lane];
    if (lane == STOP_TAG || lane == START_TAG) vv = NEGV;
    term[lane] = vv;
  }
  __syncthreads();
  if (lane == 0) {
    float best = term[0]; int arg = 0;
    for (int j = 1; j < NTAG; ++j)
      if (term[j] > best) { best = term[j]; arg = j; }
    out[b] = best;
    int cur = arg;
    for (int s = SS - 1; s >= 0; --s) {
      out[64 + (size_t)b * SS + s] = (float)cur;
      cur = bp[s][cur];
    }
  }
}

// ---------------- launch ---------------------------------------------------
extern "C" void kernel_launch(void* const* d_in, const int* in_sizes, int n_in,
                              void* d_out, int out_size, void* d_ws, size_t ws_size,
                              hipStream_t stream) {
  (void)in_sizes; (void)n_in; (void)out_size;
  const int*   sent  = (const int*)d_in[0];
  const float* emb   = (const float*)d_in[4];
  const float* WihF  = (const float*)d_in[5];
  const float* WhhF  = (const float*)d_in[6];
  const float* bihF  = (const float*)d_in[7];
  const float* bhhF  = (const float*)d_in[8];
  const float* WihB  = (const float*)d_in[9];
  const float* WhhB  = (const float*)d_in[10];
  const float* bihB  = (const float*)d_in[11];
  const float* bhhB  = (const float*)d_in[12];
  const float* Wt    = (const float*)d_in[13];
  const float* bt    = (const float*)d_in[14];
  const float* trans = (const float*)d_in[15];
  const float* h0    = (const float*)d_in[16];
  const float* c0    = (const float*)d_in[17];
  float* out = (float*)d_out;

  char* ws = (char*)d_ws;
  // layout: hx rings 512KB | pre 134.2MB | xpk 16MB | hseq 33.5MB | feats 768KB
  unsigned int* hx  = (unsigned int*)ws;          // 2 dirs * 4 slots * 64KB
  float* pre   = (float*)(ws + 524288ull);
  unsigned int* xpk = (unsigned int*)(ws + 524288ull + 134217728ull);
  float* hseq  = (float*)(ws + 524288ull + 134217728ull + 16777216ull);
  float* feats = (float*)(ws + 524288ull + 134217728ull + 16777216ull + 33554432ull);
  if (ws_size < 185860096ull) return;

  hipMemsetAsync(hx, 0xFF, 524288ull, stream);   // arm all ring slots
  k0_gather<<<SS, 256, 0, stream>>>(sent, emb, xpk);
  k1_mfma<<<8192, 256, 0, stream>>>(xpk, WihF, WihB, bihF, bhhF, bihB, bhhB, pre);
  lstm_dual<<<32, 256, 0, stream>>>(WhhF, WhhB, h0, c0, pre, hseq, hx);
  k3_feats<<<SS, 256, 0, stream>>>(hseq, Wt, bt, feats);
  k4_viterbi<<<BB, 64, 0, stream>>>(feats, trans, out);
}